// Round 1
// baseline (628.081 us; speedup 1.0000x reference)
//
#include <hip/hip_runtime.h>

// Problem: B=8, Lq=Lk=2048, D=640, fp32.
//   logits = (2*q.k - ||q||^2 - ||k||^2) / 13
//   log_attn = log_softmax(logits); attn = exp(log_attn); out = attn @ v
// Outputs concatenated in d_out: out (8*2048*640) | attn (8*2048*2048) | log_attn (8*2048*2048)

#define B_   8
#define LQ   2048
#define LK   2048
#define DD   640

typedef short s16x8 __attribute__((ext_vector_type(8)));
typedef float f32x4 __attribute__((ext_vector_type(4)));

__device__ __forceinline__ unsigned short f2bf(float x) {
    unsigned int u = __float_as_uint(x);
    unsigned int r = (u + 0x7fffu + ((u >> 16) & 1u)) >> 16;
    return (unsigned short)r;
}

// ---------------------------------------------------------------------------
// K0a: fp32 -> bf16 convert + row sum-of-squares. One wave per row (D=640).
// grid = nrows/4, block = 256.
__global__ __launch_bounds__(256) void cvt_norm(const float* __restrict__ src,
                                                unsigned short* __restrict__ dst,
                                                float* __restrict__ nrm) {
    int row  = blockIdx.x * 4 + (threadIdx.x >> 6);
    int lane = threadIdx.x & 63;
    const float4* s = (const float4*)(src + (size_t)row * DD);
    unsigned short* d = dst + (size_t)row * DD;
    float ss = 0.f;
    for (int t = lane; t < DD / 4; t += 64) {
        float4 x = s[t];
        ss += x.x * x.x + x.y * x.y + x.z * x.z + x.w * x.w;
        ushort4 o;
        o.x = f2bf(x.x); o.y = f2bf(x.y); o.z = f2bf(x.z); o.w = f2bf(x.w);
        *(ushort4*)(d + t * 4) = o;
    }
    #pragma unroll
    for (int o = 32; o; o >>= 1) ss += __shfl_xor(ss, o);
    if (lane == 0) nrm[row] = ss;
}

// ---------------------------------------------------------------------------
// K0b: v (B, 2048, 640) fp32 -> v^T (B, 640, 2048) bf16, 64x64 LDS tiles.
// grid = B * 32 * 10, block = 256.
__global__ __launch_bounds__(256) void cvt_transpose_v(const float* __restrict__ v,
                                                       unsigned short* __restrict__ vt) {
    __shared__ float tile[64][65];
    int bx = blockIdx.x;
    int b  = bx / 320;
    int r  = bx % 320;
    int tj = r / 10;   // j-tile (0..31)
    int td = r % 10;   // d-tile (0..9)
    const float* src = v + (size_t)b * LK * DD + (size_t)tj * 64 * DD + td * 64;
    for (int e = threadIdx.x; e < 4096; e += 256) {
        int rr = e >> 6, cc = e & 63;
        tile[rr][cc] = src[(size_t)rr * DD + cc];
    }
    __syncthreads();
    unsigned short* dst = vt + (size_t)b * DD * LK + (size_t)td * 64 * LK + tj * 64;
    for (int e = threadIdx.x; e < 4096; e += 256) {
        int rr = e >> 6, cc = e & 63;  // rr = local d, cc = local j
        dst[(size_t)rr * LK + cc] = f2bf(tile[cc][rr]);
    }
}

// ---------------------------------------------------------------------------
// NT-GEMM: C[i][j] = sum_d A[i][d] * B[j][d], A/B bf16 row-major (lda = LDAB),
// 128x128 tile per block, BK=64, 4 waves in 2x2, each wave 64x64 via 4x4
// mfma_f32_16x16x32_bf16. global_load_lds width-16 staging (m97 structure).
// EPI=true: val = (2*acc - qq[row] - kk[col]) / 13  (QK^T logits epilogue).
template <int LDAB, int KSZ, int NTN, bool EPI>
__global__ __launch_bounds__(256) void gemm_nt(
    const unsigned short* __restrict__ A, const unsigned short* __restrict__ Bm,
    float* __restrict__ C, size_t strideA, size_t strideB, size_t strideC, int ldc,
    const float* __restrict__ qq, const float* __restrict__ kkn) {
    __shared__ unsigned short lA[128 * 64];
    __shared__ unsigned short lB[128 * 64];
    __shared__ float snm[256];

    int bx = blockIdx.x;
    int b  = bx / (16 * NTN);
    int r  = bx % (16 * NTN);
    int tm = r / NTN, tn = r % NTN;

    const unsigned short* Ab = A + b * strideA + (size_t)tm * 128 * LDAB;
    const unsigned short* Bb = Bm + b * strideB + (size_t)tn * 128 * LDAB;

    int tid = threadIdx.x;
    int wave = tid >> 6, lane = tid & 63;

    if (EPI) {
        if (tid < 128) snm[tid] = qq[b * LQ + tm * 128 + tid];
        else           snm[tid] = kkn[b * LK + tn * 128 + (tid - 128)];
    }

    f32x4 acc[4][4] = {};
    int wm = wave >> 1, wn = wave & 1;
    int lrow = lane & 15;
    int lk8  = (lane >> 4) * 8;
    int srow = lane >> 3;        // staging: row within 8-row chunk
    int scol = (lane & 7) * 8;   // staging: bf16 col

    for (int k0 = 0; k0 < KSZ; k0 += 64) {
        __syncthreads();
        #pragma unroll
        for (int c = 0; c < 4; ++c) {
            int rbase = (c * 4 + wave) * 8;
            __builtin_amdgcn_global_load_lds(
                (const __attribute__((address_space(1))) void*)(Ab + (size_t)(rbase + srow) * LDAB + k0 + scol),
                (__attribute__((address_space(3))) void*)(lA + rbase * 64), 16, 0, 0);
            __builtin_amdgcn_global_load_lds(
                (const __attribute__((address_space(1))) void*)(Bb + (size_t)(rbase + srow) * LDAB + k0 + scol),
                (__attribute__((address_space(3))) void*)(lB + rbase * 64), 16, 0, 0);
        }
        __syncthreads();
        #pragma unroll
        for (int kk = 0; kk < 64; kk += 32) {
            s16x8 af[4], bf[4];
            #pragma unroll
            for (int t = 0; t < 4; ++t)
                af[t] = *(const s16x8*)(lA + (wm * 64 + t * 16 + lrow) * 64 + kk + lk8);
            #pragma unroll
            for (int t = 0; t < 4; ++t)
                bf[t] = *(const s16x8*)(lB + (wn * 64 + t * 16 + lrow) * 64 + kk + lk8);
            #pragma unroll
            for (int mt = 0; mt < 4; ++mt)
                #pragma unroll
                for (int nt = 0; nt < 4; ++nt)
                    acc[mt][nt] = __builtin_amdgcn_mfma_f32_16x16x32_bf16(
                        af[mt], bf[nt], acc[mt][nt], 0, 0, 0);
        }
    }

    float* Cb = C + b * strideC + (size_t)(tm * 128) * ldc + tn * 128;
    #pragma unroll
    for (int mt = 0; mt < 4; ++mt)
        #pragma unroll
        for (int nt = 0; nt < 4; ++nt) {
            int col = wn * 64 + nt * 16 + lrow;
            int rb  = wm * 64 + mt * 16 + ((lane >> 4) << 2);
            #pragma unroll
            for (int rr = 0; rr < 4; ++rr) {
                float val = acc[mt][nt][rr];
                if (EPI) val = (2.0f * val - snm[rb + rr] - snm[128 + col]) * (1.0f / 13.0f);
                Cb[(size_t)(rb + rr) * ldc + col] = val;
            }
        }
}

// ---------------------------------------------------------------------------
// K2: per-row softmax fixup. One block per (b, q-row); 2048 logits live in
// registers (8/thread). Writes attn fp32, attn bf16 (ws), log_attn (in-place).
__global__ __launch_bounds__(256) void softmax_fix(float* __restrict__ logits,
                                                   float* __restrict__ attn,
                                                   unsigned short* __restrict__ a16) {
    __shared__ float redm[4], reds[4];
    size_t row = blockIdx.x;
    float* Lr = logits + row * LK;
    int tid = threadIdx.x;
    float x[8];
    *(float4*)(x)     = *(const float4*)(Lr + tid * 8);
    *(float4*)(x + 4) = *(const float4*)(Lr + tid * 8 + 4);

    float m = x[0];
    #pragma unroll
    for (int i = 1; i < 8; ++i) m = fmaxf(m, x[i]);
    #pragma unroll
    for (int o = 32; o; o >>= 1) m = fmaxf(m, __shfl_xor(m, o));
    int wv = tid >> 6, ln = tid & 63;
    if (ln == 0) redm[wv] = m;
    __syncthreads();
    m = fmaxf(fmaxf(redm[0], redm[1]), fmaxf(redm[2], redm[3]));

    float e[8];
    float s = 0.f;
    #pragma unroll
    for (int i = 0; i < 8; ++i) { e[i] = __expf(x[i] - m); s += e[i]; }
    #pragma unroll
    for (int o = 32; o; o >>= 1) s += __shfl_xor(s, o);
    if (ln == 0) reds[wv] = s;
    __syncthreads();
    s = reds[0] + reds[1] + reds[2] + reds[3];

    float lse = __logf(s);
    float inv = 1.0f / s;
    float at[8], la[8];
    #pragma unroll
    for (int i = 0; i < 8; ++i) { at[i] = e[i] * inv; la[i] = x[i] - m - lse; }

    float* Ar = attn + row * LK;
    *(float4*)(Ar + tid * 8)     = *(float4*)at;
    *(float4*)(Ar + tid * 8 + 4) = *(float4*)(at + 4);
    *(float4*)(Lr + tid * 8)     = *(float4*)la;
    *(float4*)(Lr + tid * 8 + 4) = *(float4*)(la + 4);

    unsigned short h[8];
    #pragma unroll
    for (int i = 0; i < 8; ++i) h[i] = f2bf(at[i]);
    unsigned short* Hr = a16 + row * LK;
    *(ushort4*)(Hr + tid * 8)     = *(ushort4*)h;
    *(ushort4*)(Hr + tid * 8 + 4) = *(ushort4*)(h + 4);
}

// ---------------------------------------------------------------------------
extern "C" void kernel_launch(void* const* d_in, const int* in_sizes, int n_in,
                              void* d_out, int out_size, void* d_ws, size_t ws_size,
                              hipStream_t stream) {
    const float* q = (const float*)d_in[0];
    const float* k = (const float*)d_in[1];
    const float* v = (const float*)d_in[2];

    float* out   = (float*)d_out;                      // (8, 2048, 640)
    float* attn  = out + (size_t)B_ * LQ * DD;         // (8, 2048, 2048)
    float* logat = attn + (size_t)B_ * LQ * LK;        // (8, 2048, 2048)

    // ws layout (needs ~130.2 MB):
    unsigned short* q16  = (unsigned short*)d_ws;                 // 10485760 bf16
    unsigned short* k16  = q16 + (size_t)B_ * LQ * DD;            // 10485760
    unsigned short* v16t = k16 + (size_t)B_ * LK * DD;            // 10485760 (B, D, LK)
    unsigned short* a16  = v16t + (size_t)B_ * DD * LK;           // 33554432 (B, LQ, LK)
    float* qq  = (float*)(a16 + (size_t)B_ * LQ * LK);            // 16384
    float* kkn = qq + (size_t)B_ * LQ;                            // 16384

    cvt_norm<<<B_ * LQ / 4, 256, 0, stream>>>(q, q16, qq);
    cvt_norm<<<B_ * LK / 4, 256, 0, stream>>>(k, k16, kkn);
    cvt_transpose_v<<<B_ * (LK / 64) * (DD / 64), 256, 0, stream>>>(v, v16t);

    // QK^T -> raw logits into log_attn region. grid = 8 * 16 * 16.
    gemm_nt<DD, DD, 16, true><<<B_ * 16 * 16, 256, 0, stream>>>(
        q16, k16, logat,
        (size_t)LQ * DD, (size_t)LK * DD, (size_t)LQ * LK, LK, qq, kkn);

    // softmax fixup: one block per row.
    softmax_fix<<<B_ * LQ, 256, 0, stream>>>(logat, attn, a16);

    // PV: attn_bf16 (2048x2048) @ v^T_bf16 (640x2048) -> out. grid = 8 * 16 * 5.
    gemm_nt<LK, LK, 5, false><<<B_ * 16 * 5, 256, 0, stream>>>(
        a16, v16t, out,
        (size_t)LQ * LK, (size_t)DD * LK, (size_t)LQ * DD, DD, nullptr, nullptr);
}

// Round 2
// 625.052 us; speedup vs baseline: 1.0048x; 1.0048x over previous
//
#include <hip/hip_runtime.h>

// Problem: B=8, Lq=Lk=2048, D=640, fp32.
//   logits = (2*q.k - ||q||^2 - ||k||^2) / 13
//   log_attn = log_softmax(logits); attn = exp(log_attn); out = attn @ v
// Outputs concatenated in d_out: out (8*2048*640) | attn (8*2048*2048) | log_attn (8*2048*2048)

#define B_   8
#define LQ   2048
#define LK   2048
#define DD   640

typedef short s16x8 __attribute__((ext_vector_type(8)));
typedef float f32x4 __attribute__((ext_vector_type(4)));

__device__ __forceinline__ unsigned short f2bf(float x) {
    unsigned int u = __float_as_uint(x);
    unsigned int r = (u + 0x7fffu + ((u >> 16) & 1u)) >> 16;
    return (unsigned short)r;
}

// ---------------------------------------------------------------------------
// K0a: fp32 -> bf16 convert + row sum-of-squares for BOTH q and k in one
// launch. One wave per row (D=640). grid = 2*B*L/4, block = 256.
__global__ __launch_bounds__(256) void cvt_norm2(const float* __restrict__ q,
                                                 const float* __restrict__ k,
                                                 unsigned short* __restrict__ q16,
                                                 unsigned short* __restrict__ k16,
                                                 float* __restrict__ qq,
                                                 float* __restrict__ kkn) {
    int row  = blockIdx.x * 4 + (threadIdx.x >> 6);
    int lane = threadIdx.x & 63;
    const float* src;
    unsigned short* dst;
    float* nrm;
    int r;
    if (row < B_ * LQ) { src = q; dst = q16; nrm = qq;  r = row; }
    else               { src = k; dst = k16; nrm = kkn; r = row - B_ * LQ; }
    const float4* s = (const float4*)(src + (size_t)r * DD);
    unsigned short* d = dst + (size_t)r * DD;
    float ss = 0.f;
    for (int t = lane; t < DD / 4; t += 64) {
        float4 x = s[t];
        ss += x.x * x.x + x.y * x.y + x.z * x.z + x.w * x.w;
        ushort4 o;
        o.x = f2bf(x.x); o.y = f2bf(x.y); o.z = f2bf(x.z); o.w = f2bf(x.w);
        *(ushort4*)(d + t * 4) = o;
    }
    #pragma unroll
    for (int o = 32; o; o >>= 1) ss += __shfl_xor(ss, o);
    if (lane == 0) nrm[r] = ss;
}

// ---------------------------------------------------------------------------
// K0b: v (B, 2048, 640) fp32 -> v^T (B, 640, 2048) bf16, 64x64 LDS tiles.
// grid = B * 32 * 10, block = 256.
__global__ __launch_bounds__(256) void cvt_transpose_v(const float* __restrict__ v,
                                                       unsigned short* __restrict__ vt) {
    __shared__ float tile[64][65];
    int bx = blockIdx.x;
    int b  = bx / 320;
    int r  = bx % 320;
    int tj = r / 10;   // j-tile (0..31)
    int td = r % 10;   // d-tile (0..9)
    const float* src = v + (size_t)b * LK * DD + (size_t)tj * 64 * DD + td * 64;
    for (int e = threadIdx.x; e < 4096; e += 256) {
        int rr = e >> 6, cc = e & 63;
        tile[rr][cc] = src[(size_t)rr * DD + cc];
    }
    __syncthreads();
    unsigned short* dst = vt + (size_t)b * DD * LK + (size_t)td * 64 * LK + tj * 64;
    for (int e = threadIdx.x; e < 4096; e += 256) {
        int rr = e >> 6, cc = e & 63;  // rr = local d, cc = local j
        dst[(size_t)rr * LK + cc] = f2bf(tile[cc][rr]);
    }
}

// ---------------------------------------------------------------------------
// NT-GEMM: C[i][j] = sum_d A[i][d] * B[j][d], A/B bf16 row-major (lda = LDAB),
// 128x128 tile per block, BK=64, 4 waves in 2x2, each wave 64x64 via 4x4
// mfma_f32_16x16x32_bf16. global_load_lds width-16 staging (m97 structure).
//
// XCD-aware swizzle: workgroup->XCD is round-robin on blockIdx%8. Tie the
// M-tile index to the XCD (tm = 2*xcd + bit) so each A k-slice is fetched by
// exactly ONE XCD's L2, and co-resident blocks on an XCD sweep K in lockstep
// sharing B k-slices. Requires M-tiles == 16 (both GEMMs satisfy this).
//
// EPI=true: val = (2*acc - qq[row] - kk[col]) / 13  (QK^T logits epilogue).
template <int LDAB, int KSZ, int NTN, bool EPI>
__global__ __launch_bounds__(256) void gemm_nt(
    const unsigned short* __restrict__ A, const unsigned short* __restrict__ Bm,
    float* __restrict__ C, size_t strideA, size_t strideB, size_t strideC, int ldc,
    const float* __restrict__ qq, const float* __restrict__ kkn) {
    __shared__ unsigned short lA[128 * 64];
    __shared__ unsigned short lB[128 * 64];
    __shared__ float snm[256];

    constexpr int G = NTN * 2;          // blocks per (XCD, batch)
    int bx = blockIdx.x;
    int x  = bx & 7;                    // XCD id (heuristic: round-robin)
    int i  = bx >> 3;
    int b  = i / G;
    int j  = i % G;
    int tn = j >> 1;
    int tm = (x << 1) | (j & 1);        // M-strip owned by this XCD

    const unsigned short* Ab = A + b * strideA + (size_t)tm * 128 * LDAB;
    const unsigned short* Bb = Bm + b * strideB + (size_t)tn * 128 * LDAB;

    int tid = threadIdx.x;
    int wave = tid >> 6, lane = tid & 63;

    if (EPI) {
        if (tid < 128) snm[tid] = qq[b * LQ + tm * 128 + tid];
        else           snm[tid] = kkn[b * LK + tn * 128 + (tid - 128)];
    }

    f32x4 acc[4][4] = {};
    int wm = wave >> 1, wn = wave & 1;
    int lrow = lane & 15;
    int lk8  = (lane >> 4) * 8;
    int srow = lane >> 3;        // staging: row within 8-row chunk
    int scol = (lane & 7) * 8;   // staging: bf16 col

    for (int k0 = 0; k0 < KSZ; k0 += 64) {
        __syncthreads();
        #pragma unroll
        for (int c = 0; c < 4; ++c) {
            int rbase = (c * 4 + wave) * 8;
            __builtin_amdgcn_global_load_lds(
                (const __attribute__((address_space(1))) void*)(Ab + (size_t)(rbase + srow) * LDAB + k0 + scol),
                (__attribute__((address_space(3))) void*)(lA + rbase * 64), 16, 0, 0);
            __builtin_amdgcn_global_load_lds(
                (const __attribute__((address_space(1))) void*)(Bb + (size_t)(rbase + srow) * LDAB + k0 + scol),
                (__attribute__((address_space(3))) void*)(lB + rbase * 64), 16, 0, 0);
        }
        __syncthreads();
        #pragma unroll
        for (int kk = 0; kk < 64; kk += 32) {
            s16x8 af[4], bf[4];
            #pragma unroll
            for (int t = 0; t < 4; ++t)
                af[t] = *(const s16x8*)(lA + (wm * 64 + t * 16 + lrow) * 64 + kk + lk8);
            #pragma unroll
            for (int t = 0; t < 4; ++t)
                bf[t] = *(const s16x8*)(lB + (wn * 64 + t * 16 + lrow) * 64 + kk + lk8);
            #pragma unroll
            for (int mt = 0; mt < 4; ++mt)
                #pragma unroll
                for (int nt = 0; nt < 4; ++nt)
                    acc[mt][nt] = __builtin_amdgcn_mfma_f32_16x16x32_bf16(
                        af[mt], bf[nt], acc[mt][nt], 0, 0, 0);
        }
    }

    float* Cb = C + b * strideC + (size_t)(tm * 128) * ldc + tn * 128;
    #pragma unroll
    for (int mt = 0; mt < 4; ++mt)
        #pragma unroll
        for (int nt = 0; nt < 4; ++nt) {
            int col = wn * 64 + nt * 16 + lrow;
            int rb  = wm * 64 + mt * 16 + ((lane >> 4) << 2);
            #pragma unroll
            for (int rr = 0; rr < 4; ++rr) {
                float val = acc[mt][nt][rr];
                if (EPI) val = (2.0f * val - snm[rb + rr] - snm[128 + col]) * (1.0f / 13.0f);
                Cb[(size_t)(rb + rr) * ldc + col] = val;
            }
        }
}

// ---------------------------------------------------------------------------
// K2: per-row softmax fixup. One block per (b, q-row); 2048 logits live in
// registers (8/thread). Writes attn fp32, attn bf16 (ws), log_attn (in-place).
__global__ __launch_bounds__(256) void softmax_fix(float* __restrict__ logits,
                                                   float* __restrict__ attn,
                                                   unsigned short* __restrict__ a16) {
    __shared__ float redm[4], reds[4];
    size_t row = blockIdx.x;
    float* Lr = logits + row * LK;
    int tid = threadIdx.x;
    float x[8];
    *(float4*)(x)     = *(const float4*)(Lr + tid * 8);
    *(float4*)(x + 4) = *(const float4*)(Lr + tid * 8 + 4);

    float m = x[0];
    #pragma unroll
    for (int i = 1; i < 8; ++i) m = fmaxf(m, x[i]);
    #pragma unroll
    for (int o = 32; o; o >>= 1) m = fmaxf(m, __shfl_xor(m, o));
    int wv = tid >> 6, ln = tid & 63;
    if (ln == 0) redm[wv] = m;
    __syncthreads();
    m = fmaxf(fmaxf(redm[0], redm[1]), fmaxf(redm[2], redm[3]));

    float e[8];
    float s = 0.f;
    #pragma unroll
    for (int i = 0; i < 8; ++i) { e[i] = __expf(x[i] - m); s += e[i]; }
    #pragma unroll
    for (int o = 32; o; o >>= 1) s += __shfl_xor(s, o);
    if (ln == 0) reds[wv] = s;
    __syncthreads();
    s = reds[0] + reds[1] + reds[2] + reds[3];

    float lse = __logf(s);
    float inv = 1.0f / s;
    float at[8], la[8];
    #pragma unroll
    for (int i = 0; i < 8; ++i) { at[i] = e[i] * inv; la[i] = x[i] - m - lse; }

    float* Ar = attn + row * LK;
    *(float4*)(Ar + tid * 8)     = *(float4*)at;
    *(float4*)(Ar + tid * 8 + 4) = *(float4*)(at + 4);
    *(float4*)(Lr + tid * 8)     = *(float4*)la;
    *(float4*)(Lr + tid * 8 + 4) = *(float4*)(la + 4);

    unsigned short h[8];
    #pragma unroll
    for (int i = 0; i < 8; ++i) h[i] = f2bf(at[i]);
    unsigned short* Hr = a16 + row * LK;
    *(ushort4*)(Hr + tid * 8)     = *(ushort4*)h;
    *(ushort4*)(Hr + tid * 8 + 4) = *(ushort4*)(h + 4);
}

// ---------------------------------------------------------------------------
extern "C" void kernel_launch(void* const* d_in, const int* in_sizes, int n_in,
                              void* d_out, int out_size, void* d_ws, size_t ws_size,
                              hipStream_t stream) {
    const float* q = (const float*)d_in[0];
    const float* k = (const float*)d_in[1];
    const float* v = (const float*)d_in[2];

    float* out   = (float*)d_out;                      // (8, 2048, 640)
    float* attn  = out + (size_t)B_ * LQ * DD;         // (8, 2048, 2048)
    float* logat = attn + (size_t)B_ * LQ * LK;        // (8, 2048, 2048)

    // ws layout (needs ~130.2 MB):
    unsigned short* q16  = (unsigned short*)d_ws;                 // 10485760 bf16
    unsigned short* k16  = q16 + (size_t)B_ * LQ * DD;            // 10485760
    unsigned short* v16t = k16 + (size_t)B_ * LK * DD;            // 10485760 (B, D, LK)
    unsigned short* a16  = v16t + (size_t)B_ * DD * LK;           // 33554432 (B, LQ, LK)
    float* qq  = (float*)(a16 + (size_t)B_ * LQ * LK);            // 16384
    float* kkn = qq + (size_t)B_ * LQ;                            // 16384

    cvt_norm2<<<2 * B_ * LQ / 4, 256, 0, stream>>>(q, k, q16, k16, qq, kkn);
    cvt_transpose_v<<<B_ * (LK / 64) * (DD / 64), 256, 0, stream>>>(v, v16t);

    // QK^T -> raw logits into log_attn region. grid = 8 * 16 * 16.
    gemm_nt<DD, DD, 16, true><<<B_ * 16 * 16, 256, 0, stream>>>(
        q16, k16, logat,
        (size_t)LQ * DD, (size_t)LK * DD, (size_t)LQ * LK, LK, qq, kkn);

    // softmax fixup: one block per row.
    softmax_fix<<<B_ * LQ, 256, 0, stream>>>(logat, attn, a16);

    // PV: attn_bf16 (2048x2048) @ v^T_bf16 (640x2048) -> out. grid = 8 * 16 * 5.
    gemm_nt<LK, LK, 5, false><<<B_ * 16 * 5, 256, 0, stream>>>(
        a16, v16t, out,
        (size_t)LQ * LK, (size_t)DD * LK, (size_t)LQ * DD, DD, nullptr, nullptr);
}